// Round 9
// baseline (353.777 us; speedup 1.0000x reference)
//
#include <hip/hip_runtime.h>
#include <hip/hip_bf16.h>

#define M 2048
#define N 131072
#define D 256

#define SLICE_G 64                     // 16-n-groups per slice = 1024 n = 512 KB f16
#define NWG     (SLICE_G / 2)          // 32 wide groups (32 n each)
#define NSLICE  (N / (SLICE_G * 16))   // 128
#define BIAS    1024.0f                // score = vsq+BIAS-2qv > 0 -> uint-sortable bits

typedef __attribute__((ext_vector_type(8))) _Float16 half8;  // 8 f16 (4 VGPRs)
typedef __attribute__((ext_vector_type(8))) short short8;
typedef __attribute__((ext_vector_type(4))) float f32x4;     // MFMA acc
typedef unsigned long long ull;

__device__ __forceinline__ ull pack_key(float score, unsigned idx) {
    unsigned u = __float_as_uint(score);
    u = (u & 0x80000000u) ? ~u : (u | 0x80000000u);
    return ((ull)u << 32) | idx;
}

// ---------------- Kernel A (fused): V and Q -> f16 FRAGMENT-LINEAR, coalesced ----------
// Frag-linear: row-group g, chunk c (k=c*32..31) -> 1KB tile at xf[(g*8+c)*512];
// lane l=quad*16+tx holds row g*16+tx, k=c*32+quad*8..+7 (MFMA A/B frag order).
__global__ __launch_bounds__(256) void convert_fused(const float* __restrict__ v,
                                                     const float* __restrict__ q,
                                                     short* __restrict__ vf,
                                                     short* __restrict__ qf,
                                                     float* __restrict__ vsqb,
                                                     ull* __restrict__ keys) {
    __shared__ float lds[16 * 260];
    __shared__ float part[4][16];

    const int b    = blockIdx.x;
    const bool isV = (b < N / 16);
    const int g    = isV ? b : (b - N / 16);
    const float* x = isV ? v : q;
    short* xf      = isV ? vf : qf;

    const int t    = threadIdx.x;
    const int w    = t >> 6;
    const int l    = t & 63;
    const int quad = (l >> 4) & 3;
    const int tx   = l & 15;

    const float* src = x + (size_t)g * 4096;
#pragma unroll
    for (int i = 0; i < 4; ++i) {
        const int fi  = (i * 256 + t) * 4;
        const float4 f = *(const float4*)(src + fi);
        const int row = fi >> 8;
        const int col = fi & 255;
        *(float4*)&lds[row * 260 + col] = f;
    }
    __syncthreads();

    float s = 0.f;
#pragma unroll
    for (int h = 0; h < 2; ++h) {
        const int c = w + h * 4;
        float tmp[8] __attribute__((aligned(16)));
        *(float4*)&tmp[0] = *(const float4*)&lds[tx * 260 + c * 32 + quad * 8];
        *(float4*)&tmp[4] = *(const float4*)&lds[tx * 260 + c * 32 + quad * 8 + 4];
        half8 hh;
#pragma unroll
        for (int e = 0; e < 8; ++e) {
            hh[e] = (_Float16)tmp[e];
            s += tmp[e] * tmp[e];
        }
        *(short8*)(xf + ((size_t)g * 8 + c) * 512 + l * 8) = *(short8*)&hh;
    }

    if (isV) {
        s += __shfl_xor(s, 16, 64);
        s += __shfl_xor(s, 32, 64);
        if (l < 16) part[w][l] = s;
        __syncthreads();
        if (t < 16) vsqb[g * 16 + t] = part[0][t] + part[1][t] + part[2][t] + part[3][t] + BIAS;
    } else if (g == 0) {
        for (int i = t; i < 2 * M; i += 256) keys[i] = ~0ull;
    }
}

// ---------------- Kernel B: A-in-LDS, B ping-pong from global, barrier-free K-loop -----
// Block = 128 q-rows staged frag-linear in 64KB LDS (occupancy LDS-capped at 2 blk/CU
// -> register allocator keeps A-frags + B ping-pong resident instead of reloading).
// Wave = 32 q-rows x 32-n wide groups; per wide group: 16 B b128 loads (contiguous
// 16KB), 32 MFMA, min-tracking epilogue. One __syncthreads in the whole kernel.
__global__ __launch_bounds__(256, 2) void dist_argmin_reg(const short* __restrict__ qf,
                                                          const short* __restrict__ vf,
                                                          const float* __restrict__ vsqb,
                                                          ull* __restrict__ keys1,
                                                          ull* __restrict__ keys2) {
    __shared__ __align__(16) short sA[128 * 256];   // 64 KB, frag-linear

    const int tid  = threadIdx.x;
    const int lane = tid & 63;
    const int w    = tid >> 6;
    const int tx   = lane & 15;
    const int quad = (lane >> 4) & 3;

    // XCD swizzle: 2048 blocks; lb%8 = XCD; each XCD owns 16 slices (8 MB of vf)
    const int lb    = blockIdx.x;
    const int xcd   = lb & 7;
    const int s_    = lb >> 3;              // 0..255
    const int slice = xcd * 16 + (s_ >> 4);
    const int qblk  = s_ & 15;

    const int qb0 = qblk * 128 + w * 32;    // wave's first q-row
    const int sg0 = slice * SLICE_G;

    // Stage block's A (128 rows, frag-linear = contiguous 64KB of qf): coalesced
    {
        const short* qsrc = qf + (size_t)qblk * 32768;
#pragma unroll
        for (int i = 0; i < 16; ++i) {
            const int off = (i * 256 + tid) * 8;
            *(short8*)(sA + off) = *(const short8*)(qsrc + off);
        }
    }
    __syncthreads();

    // A-frags: 2 strips x 8 chunks, from LDS (cheap to rematerialize if spilled)
    half8 aq[2][8];
#pragma unroll
    for (int mt = 0; mt < 2; ++mt)
#pragma unroll
        for (int c = 0; c < 8; ++c)
            aq[mt][c] = *(const half8*)(sA + ((2 * w + mt) * 8 + c) * 512 + lane * 8);

    unsigned best[8];
#pragma unroll
    for (int i = 0; i < 8; ++i) best[i] = 0xFFFFFFFFu;

    const short* bp = vf + ((size_t)sg0 * 8) * 512 + lane * 8;
    const float* vp = vsqb + sg0 * 16 + tx;

    half8 bA[16], bB[16];     // ping-pong wide-group B (128 VGPRs)
    float vA0, vA1, vB0, vB1;

    auto loadwg = [&](half8* b, float& v0, float& v1, int wg) {
        const short* p = bp + (size_t)wg * 8192;
#pragma unroll
        for (int c = 0; c < 8; ++c) {
            b[c]     = *(const half8*)(p + c * 512);
            b[8 + c] = *(const half8*)(p + 4096 + c * 512);
        }
        v0 = vp[(2 * wg) * 16];
        v1 = vp[(2 * wg + 1) * 16];
    };
    auto compute = [&](const half8* b, float v0, float v1, int wg) {
        f32x4 acc[2][2];   // [strip][n-group]: 4 independent chains, dep distance 8
#pragma unroll
        for (int i = 0; i < 2; ++i) {
            acc[i][0] = (f32x4){0.f, 0.f, 0.f, 0.f};
            acc[i][1] = (f32x4){0.f, 0.f, 0.f, 0.f};
        }
#pragma unroll
        for (int c = 0; c < 8; ++c)
#pragma unroll
            for (int mt = 0; mt < 2; ++mt) {
                acc[mt][0] = __builtin_amdgcn_mfma_f32_16x16x32_f16(aq[mt][c], b[c],     acc[mt][0], 0, 0, 0);
                acc[mt][1] = __builtin_amdgcn_mfma_f32_16x16x32_f16(aq[mt][c], b[8 + c], acc[mt][1], 0, 0, 0);
            }
#pragma unroll
        for (int mt = 0; mt < 2; ++mt)
#pragma unroll
            for (int r = 0; r < 4; ++r) {
                const float s0 = fmaf(-2.f, acc[mt][0][r], v0);
                const float s1 = fmaf(-2.f, acc[mt][1][r], v1);
                const unsigned k0 = (__float_as_uint(s0) & 0xFFFFFFC0u) | (unsigned)(2 * wg);
                const unsigned k1 = (__float_as_uint(s1) & 0xFFFFFFC0u) | (unsigned)(2 * wg + 1);
                const int sl = mt * 4 + r;
                unsigned m = k0 < k1 ? k0 : k1;
                best[sl] = m < best[sl] ? m : best[sl];
            }
    };

    loadwg(bA, vA0, vA1, 0);
    for (int wg = 0; wg < NWG - 2; wg += 2) {
        loadwg(bB, vB0, vB1, wg + 1);
        compute(bA, vA0, vA1, wg);
        loadwg(bA, vA0, vA1, wg + 2);
        compute(bB, vB0, vB1, wg + 1);
    }
    loadwg(bB, vB0, vB1, NWG - 1);
    compute(bA, vA0, vA1, NWG - 2);
    compute(bB, vB0, vB1, NWG - 1);

    // Epilogue: per slot, min across 16 tx lanes; recover (g, tx); top-2 insert.
#pragma unroll
    for (int mt = 0; mt < 2; ++mt)
#pragma unroll
        for (int r = 0; r < 4; ++r) {
            const int sl = mt * 4 + r;
            unsigned k = best[sl];
#pragma unroll
            for (int off = 8; off; off >>= 1) {
                const unsigned o = (unsigned)__shfl_xor((int)k, off, 16);
                k = o < k ? o : k;
            }
            const ull bal = __ballot(best[sl] == k);
            const unsigned grp = (unsigned)((bal >> (quad * 16)) & 0xFFFFull);
            const int wtx = __ffs((int)grp) - 1;
            const unsigned n = (unsigned)((sg0 + (int)(k & 63u)) * 16 + wtx);
            if (tx == 0) {
                const int row = qb0 + mt * 16 + quad * 4 + r;
                const ull key64 = ((ull)k << 32) | n;
                const ull old = atomicMin(&keys1[row], key64);
                const ull loser = (key64 < old) ? old : key64;
                if (loser != ~0ull) atomicMin(&keys2[row], loser);
            }
        }
}

// ---------------- Kernel C: exact fp32 rescore of approx top-2 ----------------
__global__ __launch_bounds__(256) void rescore_kernel(const float* __restrict__ q,
                                                      const float* __restrict__ v,
                                                      const ull* __restrict__ keys1,
                                                      const ull* __restrict__ keys2,
                                                      int* __restrict__ out) {
    const int qi   = blockIdx.x * 4 + (threadIdx.x >> 6);
    const int lane = threadIdx.x & 63;
    const float4 qv = *(const float4*)(q + (size_t)qi * D + lane * 4);
    ull best = ~0ull;
    ull cand[2];
    cand[0] = keys1[qi];
    cand[1] = keys2[qi];
#pragma unroll
    for (int c = 0; c < 2; ++c) {
        if (cand[c] == ~0ull) continue;
        const unsigned idx = (unsigned)cand[c];
        const float4 vv = *(const float4*)(v + (size_t)idx * D + lane * 4);
        float s1 = vv.x * vv.x + vv.y * vv.y + vv.z * vv.z + vv.w * vv.w;   // ||v||^2
        float s2 = qv.x * vv.x + qv.y * vv.y + qv.z * vv.z + qv.w * vv.w;   // q.v
#pragma unroll
        for (int off = 32; off; off >>= 1) {
            s1 += __shfl_xor(s1, off, 64);
            s2 += __shfl_xor(s2, off, 64);
        }
        const float dist = fmaf(-2.0f, s2, s1);   // exact fp32 (sans ||q||^2)
        const ull key = pack_key(dist, idx);
        best = best < key ? best : key;
    }
    if (lane == 0) out[qi] = (int)(unsigned)(best & 0xFFFFFFFFull);
}

extern "C" void kernel_launch(void* const* d_in, const int* in_sizes, int n_in,
                              void* d_out, int out_size, void* d_ws, size_t ws_size,
                              hipStream_t stream) {
    const float* q = (const float*)d_in[0];
    const float* v = (const float*)d_in[1];
    int* out = (int*)d_out;

    char* ws = (char*)d_ws;
    float* vsqb = (float*)ws;                ws += (size_t)N * sizeof(float);
    ull* keys1 = (ull*)ws;                   ws += (size_t)2 * M * sizeof(ull);
    ull* keys2 = keys1 + M;
    short* qf = (short*)ws;                  ws += (size_t)M * D * 2;
    short* vf = (short*)ws;                  // 64 MB frag-linear

    convert_fused<<<N / 16 + M / 16, 256, 0, stream>>>(v, q, vf, qf, vsqb, keys1);

    dist_argmin_reg<<<(M / 128) * NSLICE, 256, 0, stream>>>(qf, vf, vsqb, keys1, keys2);

    rescore_kernel<<<M / 4, 256, 0, stream>>>(q, v, keys1, keys2, out);
}

// Round 10
// 322.216 us; speedup vs baseline: 1.0979x; 1.0979x over previous
//
#include <hip/hip_runtime.h>
#include <hip/hip_bf16.h>

#define M 2048
#define N 131072
#define D 256

#define SLICE_G 64                     // n-groups (of 16) per slice = 1024 n = 512 KB f16
#define NSLICE  (N / (SLICE_G * 16))   // 128
#define BIAS    1024.0f                // score = vsq+BIAS-2qv > 0 -> uint-sortable bits

typedef __attribute__((ext_vector_type(8))) _Float16 half8;  // 8 f16 (4 VGPRs)
typedef __attribute__((ext_vector_type(8))) short short8;
typedef __attribute__((ext_vector_type(4))) float f32x4;     // MFMA acc
typedef unsigned long long ull;

__device__ __forceinline__ ull pack_key(float score, unsigned idx) {
    unsigned u = __float_as_uint(score);
    u = (u & 0x80000000u) ? ~u : (u | 0x80000000u);
    return ((ull)u << 32) | idx;
}

// ---------------- Kernel A (fused): V and Q -> f16 FRAGMENT-LINEAR, coalesced ----------
// Frag-linear: row-group g, chunk c (k=c*32..31) -> 1KB tile at xf[(g*8+c)*512];
// lane l=quad*16+tx holds row g*16+tx, k=c*32+quad*8..+7 (MFMA A/B frag order).
__global__ __launch_bounds__(256) void convert_fused(const float* __restrict__ v,
                                                     const float* __restrict__ q,
                                                     short* __restrict__ vf,
                                                     short* __restrict__ qf,
                                                     float* __restrict__ vsqb,
                                                     ull* __restrict__ keys) {
    __shared__ float lds[16 * 260];
    __shared__ float part[4][16];

    const int b    = blockIdx.x;
    const bool isV = (b < N / 16);
    const int g    = isV ? b : (b - N / 16);
    const float* x = isV ? v : q;
    short* xf      = isV ? vf : qf;

    const int t    = threadIdx.x;
    const int w    = t >> 6;
    const int l    = t & 63;
    const int quad = (l >> 4) & 3;
    const int tx   = l & 15;

    const float* src = x + (size_t)g * 4096;
#pragma unroll
    for (int i = 0; i < 4; ++i) {
        const int fi  = (i * 256 + t) * 4;
        const float4 f = *(const float4*)(src + fi);
        const int row = fi >> 8;
        const int col = fi & 255;
        *(float4*)&lds[row * 260 + col] = f;
    }
    __syncthreads();

    float s = 0.f;
#pragma unroll
    for (int h = 0; h < 2; ++h) {
        const int c = w + h * 4;
        float tmp[8] __attribute__((aligned(16)));
        *(float4*)&tmp[0] = *(const float4*)&lds[tx * 260 + c * 32 + quad * 8];
        *(float4*)&tmp[4] = *(const float4*)&lds[tx * 260 + c * 32 + quad * 8 + 4];
        half8 hh;
#pragma unroll
        for (int e = 0; e < 8; ++e) {
            hh[e] = (_Float16)tmp[e];
            s += tmp[e] * tmp[e];
        }
        *(short8*)(xf + ((size_t)g * 8 + c) * 512 + l * 8) = *(short8*)&hh;
    }

    if (isV) {
        s += __shfl_xor(s, 16, 64);
        s += __shfl_xor(s, 32, 64);
        if (l < 16) part[w][l] = s;
        __syncthreads();
        if (t < 16) vsqb[g * 16 + t] = part[0][t] + part[1][t] + part[2][t] + part[3][t] + BIAS;
    } else if (g == 0) {
        for (int i = t; i < 2 * M; i += 256) keys[i] = ~0ull;
    }
}

// ---------------- Kernel B: 64 q-rows/wave, REGISTER-RESIDENT A, pinned occupancy ------
// amdgpu_waves_per_eu(2,2): min=max=2 waves/EU -> 256-VGPR budget, scheduler has no
// occupancy incentive to sink the A-frag loads (r6-r9 failure mode: VGPR ~100-124,
// A re-streamed from global every group -> VMEM-return-bound at ~51 B/cyc/CU).
// aq[4][8]=128 VGPR + B ping-pong 64 + acc/addr ~40 = ~230 resident.
__global__ __launch_bounds__(256)
__attribute__((amdgpu_waves_per_eu(2, 2)))
void dist_argmin_reg(const short* __restrict__ qf,
                     const short* __restrict__ vf,
                     const float* __restrict__ vsqb,
                     ull* __restrict__ keys1,
                     ull* __restrict__ keys2) {
    const int tid  = threadIdx.x;
    const int lane = tid & 63;
    const int w    = tid >> 6;
    const int tx   = lane & 15;
    const int quad = (lane >> 4) & 3;

    // XCD swizzle: 1024 blocks; lb%8 = XCD; each XCD owns 16 slices (8 MB of vf)
    const int lb    = blockIdx.x;
    const int xcd   = lb & 7;
    const int s_    = lb >> 3;              // 0..127 within XCD
    const int slice = xcd * 16 + (s_ >> 3);
    const int qblk  = s_ & 7;

    const int qb0 = qblk * 256 + w * 64;    // wave's first q-row (64 rows)
    const int sg0 = slice * SLICE_G;

    half8 aq[4][8];                         // 128 VGPRs, loaded once, stays resident
#pragma unroll
    for (int mt = 0; mt < 4; ++mt)
#pragma unroll
        for (int c = 0; c < 8; ++c)
            aq[mt][c] = *(const half8*)(qf + ((size_t)((qb0 >> 4) + mt) * 8 + c) * 512 + lane * 8);

    unsigned best[16];
#pragma unroll
    for (int i = 0; i < 16; ++i) best[i] = 0xFFFFFFFFu;

    const short* bp = vf + ((size_t)sg0 * 8) * 512 + lane * 8;
    const float* vp = vsqb + sg0 * 16 + tx;

    half8 bA[8], bB[8];
    float vA, vB;

    auto loadg = [&](half8* b, float& vs, int g) {
        const short* p = bp + (size_t)g * 4096;
#pragma unroll
        for (int c = 0; c < 8; ++c) b[c] = *(const half8*)(p + c * 512);
        vs = vp[g * 16];
    };
    auto compute = [&](const half8* b, float vsqr, int g) {
        f32x4 acc[4];                        // 4 independent chains, dep distance 4
#pragma unroll
        for (int i = 0; i < 4; ++i) acc[i] = (f32x4){0.f, 0.f, 0.f, 0.f};
#pragma unroll
        for (int c = 0; c < 8; ++c)
#pragma unroll
            for (int mt = 0; mt < 4; ++mt)
                acc[mt] = __builtin_amdgcn_mfma_f32_16x16x32_f16(aq[mt][c], b[c], acc[mt], 0, 0, 0);
#pragma unroll
        for (int mt = 0; mt < 4; ++mt)
#pragma unroll
            for (int r = 0; r < 4; ++r) {
                const float sc = fmaf(-2.f, acc[mt][r], vsqr);
                const unsigned key = (__float_as_uint(sc) & 0xFFFFFFC0u) | (unsigned)g;
                const int sl = mt * 4 + r;
                best[sl] = key < best[sl] ? key : best[sl];
            }
    };

    loadg(bA, vA, 0);
    for (int g = 0; g < SLICE_G - 2; g += 2) {
        loadg(bB, vB, g + 1);
        compute(bA, vA, g);
        loadg(bA, vA, g + 2);
        compute(bB, vB, g + 1);
    }
    loadg(bB, vB, SLICE_G - 1);
    compute(bA, vA, SLICE_G - 2);
    compute(bB, vB, SLICE_G - 1);

    // Epilogue: per slot, min across 16 tx lanes; recover (g, tx); top-2 insert.
#pragma unroll
    for (int mt = 0; mt < 4; ++mt)
#pragma unroll
        for (int r = 0; r < 4; ++r) {
            const int sl = mt * 4 + r;
            unsigned k = best[sl];
#pragma unroll
            for (int off = 8; off; off >>= 1) {
                const unsigned o = (unsigned)__shfl_xor((int)k, off, 16);
                k = o < k ? o : k;
            }
            const ull bal = __ballot(best[sl] == k);
            const unsigned grp = (unsigned)((bal >> (quad * 16)) & 0xFFFFull);
            const int wtx = __ffs((int)grp) - 1;
            const unsigned n = (unsigned)((sg0 + (int)(k & 63u)) * 16 + wtx);
            if (tx == 0) {
                const int row = qb0 + mt * 16 + quad * 4 + r;
                const ull key64 = ((ull)k << 32) | n;
                const ull old = atomicMin(&keys1[row], key64);
                const ull loser = (key64 < old) ? old : key64;
                if (loser != ~0ull) atomicMin(&keys2[row], loser);
            }
        }
}

// ---------------- Kernel C: exact fp32 rescore of approx top-2 ----------------
__global__ __launch_bounds__(256) void rescore_kernel(const float* __restrict__ q,
                                                      const float* __restrict__ v,
                                                      const ull* __restrict__ keys1,
                                                      const ull* __restrict__ keys2,
                                                      int* __restrict__ out) {
    const int qi   = blockIdx.x * 4 + (threadIdx.x >> 6);
    const int lane = threadIdx.x & 63;
    const float4 qv = *(const float4*)(q + (size_t)qi * D + lane * 4);
    ull best = ~0ull;
    ull cand[2];
    cand[0] = keys1[qi];
    cand[1] = keys2[qi];
#pragma unroll
    for (int c = 0; c < 2; ++c) {
        if (cand[c] == ~0ull) continue;
        const unsigned idx = (unsigned)cand[c];
        const float4 vv = *(const float4*)(v + (size_t)idx * D + lane * 4);
        float s1 = vv.x * vv.x + vv.y * vv.y + vv.z * vv.z + vv.w * vv.w;   // ||v||^2
        float s2 = qv.x * vv.x + qv.y * vv.y + qv.z * vv.z + qv.w * vv.w;   // q.v
#pragma unroll
        for (int off = 32; off; off >>= 1) {
            s1 += __shfl_xor(s1, off, 64);
            s2 += __shfl_xor(s2, off, 64);
        }
        const float dist = fmaf(-2.0f, s2, s1);   // exact fp32 (sans ||q||^2)
        const ull key = pack_key(dist, idx);
        best = best < key ? best : key;
    }
    if (lane == 0) out[qi] = (int)(unsigned)(best & 0xFFFFFFFFull);
}

extern "C" void kernel_launch(void* const* d_in, const int* in_sizes, int n_in,
                              void* d_out, int out_size, void* d_ws, size_t ws_size,
                              hipStream_t stream) {
    const float* q = (const float*)d_in[0];
    const float* v = (const float*)d_in[1];
    int* out = (int*)d_out;

    char* ws = (char*)d_ws;
    float* vsqb = (float*)ws;                ws += (size_t)N * sizeof(float);
    ull* keys1 = (ull*)ws;                   ws += (size_t)2 * M * sizeof(ull);
    ull* keys2 = keys1 + M;
    short* qf = (short*)ws;                  ws += (size_t)M * D * 2;
    short* vf = (short*)ws;                  // 64 MB frag-linear

    convert_fused<<<N / 16 + M / 16, 256, 0, stream>>>(v, q, vf, qf, vsqb, keys1);

    dist_argmin_reg<<<(M / 256) * NSLICE, 256, 0, stream>>>(qf, vf, vsqb, keys1, keys2);

    rescore_kernel<<<M / 4, 256, 0, stream>>>(q, v, keys1, keys2, out);
}